// Round 3
// baseline (99.422 us; speedup 1.0000x reference)
//
#include <hip/hip_runtime.h>

// Problem constants (from reference setup_inputs)
constexpr int cB = 32, cC = 6, cT = 64;
constexpr int cK = 8, cN = 128;
constexpr int cS = 32, cP = 64;
constexpr int NSEG_PAD = cK * cN;     // 1024: n==127 entries are NaN pads
constexpr int NCL  = cS * cP;         // 2048 centerline points per batch
constexpr int G = 8;                  // T-splits per (b,c): 8 points per block
constexpr int LPP = 32;               // lanes per point
constexpr float F_EPS = 1e-6f;
constexpr float F_THRESHOLD = 0.5f;

__global__ __launch_bounds__(256) void offroad_kernel(
    const float* __restrict__ points,         // (B, C, T, 2)
    const float* __restrict__ road_boundary,  // (B, K, N, 2)
    const float* __restrict__ centerlines,    // (B, S, P, 2)
    float* __restrict__ out)                  // (B, C), pre-zeroed
{
    __shared__ float4 s_seg[NSEG_PAD];   // (ax, ay, dx, dy); NaN for pads
    __shared__ float4 s_cl4[NCL / 2];    // centerline points, 2 per float4
    // total LDS = 16384 + 16384 = 32768 B -> 5 blocks/CU

    const int blk = blockIdx.x;          // 0 .. B*C*G-1
    const int g  = blk & (G - 1);
    const int bc = blk >> 3;             // b*C + c
    const int b  = bc / cC;
    const int tid = threadIdx.x;

    const float qnan = __int_as_float(0x7fc00000);

    // ---- Stage boundary segments into LDS: s = k*128 + n, n<127 valid ----
    const float2* rb2 = (const float2*)(road_boundary + (size_t)b * cK * cN * 2);
    for (int s = tid; s < NSEG_PAD; s += 256) {
        int n = s & (cN - 1);
        if (n < cN - 1) {
            float2 a  = rb2[s];
            float2 nx = rb2[s + 1];
            s_seg[s] = make_float4(a.x, a.y, nx.x - a.x, nx.y - a.y);
        } else {
            s_seg[s] = make_float4(qnan, qnan, qnan, qnan);
        }
    }
    // ---- Stage centerlines into LDS (float4 = 2 points) ----
    const float4* cl4 = (const float4*)(centerlines + (size_t)b * NCL * 2);
    for (int i = tid; i < NCL / 2; i += 256) s_cl4[i] = cl4[i];
    __syncthreads();

    // 32 lanes cooperate per point: 8 points per block
    const int t = (g << 3) | (tid >> 5);   // global point index in [0, 64)
    const int q = tid & (LPP - 1);
    const size_t pbase = (((size_t)bc) * cT + t) * 2;
    const float px = points[pbase + 0];
    const float py = points[pbase + 1];

    // ---- Fused: min point-to-segment distance + centerline argmin ----
    // Both loops have 32 iterations; fuse for ILP.
    float min_d2 = 3.4e38f;
    float best_d2 = 3.4e38f;
    int best_i = 0x7fffffff;
    #pragma unroll 4
    for (int i = 0; i < NSEG_PAD / LPP; ++i) {
        // segment distance (NaN pads fall out of fmin per IEEE)
        int s = q + i * LPP;
        float4 sg = s_seg[s];
        float v1x = px - sg.x, v1y = py - sg.y;
        float dot = v1x * sg.z + v1y * sg.w;
        float e2  = sg.z * sg.z + sg.w * sg.w + F_EPS;
        float proj = dot * __builtin_amdgcn_rcpf(e2);
        proj = fminf(fmaxf(proj, 0.0f), 1.0f);
        float ex = v1x - sg.z * proj;
        float ey = v1y - sg.w * proj;
        float d2 = ex * ex + ey * ey;
        min_d2 = fminf(min_d2, d2);

        // centerline argmin (first-index tie-break, matches jnp.argmin)
        int j = q + i * LPP;
        float4 cp = s_cl4[j];
        float dxa = px - cp.x, dya = py - cp.y;
        float d2a = dxa * dxa + dya * dya;
        float dxb = px - cp.z, dyb = py - cp.w;
        float d2b = dxb * dxb + dyb * dyb;
        int   ia = 2 * j;
        float dmin = d2a; int imin = ia;
        if (d2b < d2a) { dmin = d2b; imin = ia + 1; }  // prefer lower idx on tie
        if (dmin < best_d2 || (dmin == best_d2 && imin < best_i)) {
            best_d2 = dmin; best_i = imin;
        }
    }
    #pragma unroll
    for (int off = 1; off <= 16; off <<= 1) {
        float od2 = __shfl_xor(best_d2, off);
        int   oi  = __shfl_xor(best_i, off);
        if (od2 < best_d2 || (od2 == best_d2 && oi < best_i)) {
            best_d2 = od2; best_i = oi;
        }
    }
    const float2* s_cl2 = (const float2*)s_cl4;
    const float2 cc = s_cl2[best_i];     // all 32 lanes agree

    // ---- Segment intersection (point -> closest centerline pt) ----
    const float dax = cc.x - px, day = cc.y - py;   // da = a2 - a1
    int hit = 0;
    #pragma unroll 4
    for (int i = 0; i < NSEG_PAD / LPP; ++i) {
        int s = q + i * LPP;
        float4 sg = s_seg[s];                       // NaN pads -> compares false
        float dpx = px - sg.x, dpy = py - sg.y;     // dp = a1 - b1
        float dadb = dax * sg.w - day * sg.z;       // cross(da, db)
        float inv = __builtin_amdgcn_rcpf(dadb + F_EPS);
        float tt = (dax * dpy - day * dpx) * inv;   // cross(da, dp)/(dadb+EPS)
        float uu = (sg.z * dpy - sg.w * dpx) * inv; // cross(db, dp)/(dadb+EPS)
        hit |= (tt >= 0.0f && tt <= 1.0f && uu >= 0.0f && uu <= 1.0f) ? 1 : 0;
    }

    // ---- reduce min_d2 / hit across the 32 cooperating lanes ----
    #pragma unroll
    for (int off = 1; off <= 16; off <<= 1) {
        min_d2 = fminf(min_d2, __shfl_xor(min_d2, off));
        hit |= __shfl_xor(hit, off);
    }

    float md = sqrtf(min_d2);
    float sd = hit ? md : -md;                 // inside (no hit) -> negative
    float val = fmaxf(sd + F_THRESHOLD, 0.0f); // relu(min_dist + THRESHOLD)
    if (q != 0) val = 0.0f;                    // count each point once

    // ---- per-wave sum (2 points per wave), one atomic per wave ----
    #pragma unroll
    for (int off = 32; off >= 1; off >>= 1)
        val += __shfl_down(val, off);
    if ((tid & 63) == 0)
        atomicAdd(&out[bc], val);
}

extern "C" void kernel_launch(void* const* d_in, const int* in_sizes, int n_in,
                              void* d_out, int out_size, void* d_ws, size_t ws_size,
                              hipStream_t stream) {
    const float* points      = (const float*)d_in[0];
    const float* boundary    = (const float*)d_in[1];
    const float* centerlines = (const float*)d_in[2];
    float* out = (float*)d_out;
    hipMemsetAsync(out, 0, (size_t)out_size * sizeof(float), stream);
    offroad_kernel<<<cB * cC * G, 256, 0, stream>>>(points, boundary, centerlines, out);
}

// Round 4
// 98.687 us; speedup vs baseline: 1.0074x; 1.0074x over previous
//
#include <hip/hip_runtime.h>

// Problem constants (from reference setup_inputs)
constexpr int cB = 32, cC = 6, cT = 64;
constexpr int cK = 8, cN = 128;
constexpr int cS = 32, cP = 64;
constexpr int NSEG_PAD = cK * cN;     // 1024 slots; n==127 are pads
constexpr int NCL  = cS * cP;         // 2048 centerline points per batch
constexpr int G = 8;                  // T-splits per (b,c): 8 points per block
constexpr int LPP = 32;               // lanes per point
constexpr float F_EPS = 1e-6f;
constexpr float F_THRESHOLD = 0.5f;

// No LDS: the 16KB segment table + 16KB centerline table per batch live in
// L1 (32KB/CU) after the first pass; lanes read them stride-1 coalesced.
// This removes the staging loop, the barrier, and the LDS occupancy cap.
__global__ __launch_bounds__(256, 8) void offroad_kernel(
    const float* __restrict__ points,         // (B, C, T, 2)
    const float* __restrict__ road_boundary,  // (B, K, N, 2)
    const float* __restrict__ centerlines,    // (B, S, P, 2)
    float* __restrict__ out)                  // (B, C), pre-zeroed
{
    const int blk = blockIdx.x;          // 0 .. B*C*G-1
    const int g  = blk & (G - 1);
    const int bc = blk >> 3;             // b*C + c
    const int b  = bc / cC;
    const int tid = threadIdx.x;

    const float2* __restrict__ rb2 =
        (const float2*)(road_boundary + (size_t)b * cK * cN * 2);
    const float4* __restrict__ cl4 =
        (const float4*)(centerlines + (size_t)b * NCL * 2);

    // 32 lanes cooperate per point: 8 points per block, 2 per wave
    const int t = (g << 3) | (tid >> 5);   // global point index in [0, 64)
    const int q = tid & (LPP - 1);
    const size_t pbase = (((size_t)bc) * cT + t) * 2;
    const float px = points[pbase + 0];
    const float py = points[pbase + 1];

    // ---- Fused: min point-to-segment distance + centerline argmin ----
    float min_d2  = 3.4e38f;
    float best_d2 = 3.4e38f;
    int   best_i  = 0x7fffffff;
    #pragma unroll 4
    for (int i = 0; i < NSEG_PAD / LPP; ++i) {
        const int s = q + i * LPP;
        const int n = s & (cN - 1);
        // pad lanes (n==127): s1=s -> d=0 -> distance to polyline endpoint,
        // which is >= the adjacent real segment's distance -> min unaffected.
        const int s1 = s + ((n < cN - 1) ? 1 : 0);
        float2 a  = rb2[s];
        float2 nx = rb2[s1];
        float dx = nx.x - a.x, dy = nx.y - a.y;
        float v1x = px - a.x,  v1y = py - a.y;
        float dot = v1x * dx + v1y * dy;
        float e2  = dx * dx + dy * dy + F_EPS;
        float proj = dot * __builtin_amdgcn_rcpf(e2);
        proj = fminf(fmaxf(proj, 0.0f), 1.0f);
        float ex = v1x - dx * proj;
        float ey = v1y - dy * proj;
        min_d2 = fminf(min_d2, ex * ex + ey * ey);

        // centerline argmin (first-index tie-break, matches jnp.argmin)
        float4 cp = cl4[s];                   // s spans 0..1023 == NCL/2
        float dxa = px - cp.x, dya = py - cp.y;
        float d2a = dxa * dxa + dya * dya;
        float dxb = px - cp.z, dyb = py - cp.w;
        float d2b = dxb * dxb + dyb * dyb;
        int   ia = 2 * s;
        float dmin = d2a; int imin = ia;
        if (d2b < d2a) { dmin = d2b; imin = ia + 1; }  // prefer lower idx on tie
        if (dmin < best_d2 || (dmin == best_d2 && imin < best_i)) {
            best_d2 = dmin; best_i = imin;
        }
    }
    #pragma unroll
    for (int off = 1; off <= 16; off <<= 1) {
        float od2 = __shfl_xor(best_d2, off);
        int   oi  = __shfl_xor(best_i, off);
        if (od2 < best_d2 || (od2 == best_d2 && oi < best_i)) {
            best_d2 = od2; best_i = oi;
        }
    }
    const float2 cc = ((const float2*)cl4)[best_i];  // broadcast load, L1-hot

    // ---- Segment intersection (point -> closest centerline pt) ----
    const float dax = cc.x - px, day = cc.y - py;    // da = a2 - a1
    int hit = 0;
    #pragma unroll 4
    for (int i = 0; i < NSEG_PAD / LPP; ++i) {
        const int s = q + i * LPP;
        const int n = s & (cN - 1);
        const int s1 = s + ((n < cN - 1) ? 1 : 0);
        float2 a  = rb2[s];
        float2 nx = rb2[s1];
        float dbx = nx.x - a.x, dby = nx.y - a.y;    // db
        float dpx = px - a.x,   dpy = py - a.y;      // dp = a1 - b1
        float dadb = dax * dby - day * dbx;          // cross(da, db)
        float inv = __builtin_amdgcn_rcpf(dadb + F_EPS);
        float tt = (dax * dpy - day * dpx) * inv;    // cross(da, dp)/(dadb+EPS)
        float uu = (dbx * dpy - dby * dpx) * inv;    // cross(db, dp)/(dadb+EPS)
        bool inb = (tt >= 0.0f) & (tt <= 1.0f) & (uu >= 0.0f) & (uu <= 1.0f);
        hit |= (int)((n < cN - 1) & inb);
    }

    // ---- reduce min_d2 / hit across the 32 cooperating lanes ----
    #pragma unroll
    for (int off = 1; off <= 16; off <<= 1) {
        min_d2 = fminf(min_d2, __shfl_xor(min_d2, off));
        hit |= __shfl_xor(hit, off);
    }

    float md = sqrtf(min_d2);
    float sd = hit ? md : -md;                 // inside (no hit) -> negative
    float val = fmaxf(sd + F_THRESHOLD, 0.0f); // relu(min_dist + THRESHOLD)
    if (q != 0) val = 0.0f;                    // count each point once

    // ---- per-wave sum (2 points per wave), one atomic per wave ----
    #pragma unroll
    for (int off = 32; off >= 1; off >>= 1)
        val += __shfl_down(val, off);
    if ((tid & 63) == 0)
        atomicAdd(&out[bc], val);
}

extern "C" void kernel_launch(void* const* d_in, const int* in_sizes, int n_in,
                              void* d_out, int out_size, void* d_ws, size_t ws_size,
                              hipStream_t stream) {
    const float* points      = (const float*)d_in[0];
    const float* boundary    = (const float*)d_in[1];
    const float* centerlines = (const float*)d_in[2];
    float* out = (float*)d_out;
    hipMemsetAsync(out, 0, (size_t)out_size * sizeof(float), stream);
    offroad_kernel<<<cB * cC * G, 256, 0, stream>>>(points, boundary, centerlines, out);
}

// Round 5
// 82.938 us; speedup vs baseline: 1.1988x; 1.1899x over previous
//
#include <hip/hip_runtime.h>

// Problem constants (from reference setup_inputs)
constexpr int cB = 32, cC = 6, cT = 64;
constexpr int cK = 8, cN = 128;
constexpr int cS = 32, cP = 64;
constexpr int NSEG_PAD = cK * cN;     // 1024 slots; n==127 are pads
constexpr int NCL  = cS * cP;         // 2048 centerline points per batch
constexpr int G = 4;                  // blocks per (b,c); 16 points per block
constexpr int PPW = 4;                // points per wave (register-blocked)
constexpr float F_EPS = 1e-6f;
constexpr float F_THRESHOLD = 0.5f;

// Structure: 768 blocks (3/CU), 256 thr = 4 waves. Each wave handles 4
// consecutive points; every segment / centerline load is reused 4x from
// registers (load:VALU ~ 1:35), so L1/L2 latency is amortized without LDS.
__global__ __launch_bounds__(256) void offroad_kernel(
    const float* __restrict__ points,         // (B, C, T, 2)
    const float* __restrict__ road_boundary,  // (B, K, N, 2)
    const float* __restrict__ centerlines,    // (B, S, P, 2)
    float* __restrict__ out)                  // (B, C), pre-zeroed
{
    const int blk  = blockIdx.x;         // 0 .. B*C*G-1
    const int g    = blk & (G - 1);
    const int bc   = blk >> 2;           // b*C + c
    const int b    = bc / cC;
    const int lane = threadIdx.x & 63;
    const int wave = threadIdx.x >> 6;

    const float2* __restrict__ rb2 =
        (const float2*)(road_boundary + (size_t)b * cK * cN * 2);
    const float4* __restrict__ cl4 =
        (const float4*)(centerlines + (size_t)b * NCL * 2);

    // 4 consecutive points for this wave (wave-uniform -> scalar loads)
    const int t0 = (g << 4) | (wave << 2);   // in [0, 64)
    const float* pb = points + (((size_t)bc) * cT + t0) * 2;
    float px[PPW], py[PPW];
    #pragma unroll
    for (int p = 0; p < PPW; ++p) { px[p] = pb[2 * p]; py[p] = pb[2 * p + 1]; }

    // ---- Fused: min point-to-segment distance + centerline argmin ----
    float min_d2[PPW], best_d2[PPW];
    int   best_i[PPW];
    #pragma unroll
    for (int p = 0; p < PPW; ++p) {
        min_d2[p] = 3.4e38f; best_d2[p] = 3.4e38f; best_i[p] = 0x7fffffff;
    }

    #pragma unroll 2
    for (int i = 0; i < NSEG_PAD / 64; ++i) {
        const int s = lane + (i << 6);
        const int n = s & (cN - 1);
        // pad lanes (n==127): s1=s -> d=0 -> distance to polyline endpoint,
        // which is >= the adjacent real segment's distance -> min unaffected.
        const int s1 = s + ((n < cN - 1) ? 1 : 0);
        const float2 a  = rb2[s];
        const float2 nx = rb2[s1];
        const float4 cp = cl4[s];            // 2 centerline points
        const float dx = nx.x - a.x, dy = nx.y - a.y;
        const float inv_e2 = __builtin_amdgcn_rcpf(dx * dx + dy * dy + F_EPS);
        const int ia = 2 * s;

        #pragma unroll
        for (int p = 0; p < PPW; ++p) {
            // point-to-segment distance
            float v1x = px[p] - a.x, v1y = py[p] - a.y;
            float proj = (v1x * dx + v1y * dy) * inv_e2;
            proj = fminf(fmaxf(proj, 0.0f), 1.0f);
            float ex = v1x - dx * proj;
            float ey = v1y - dy * proj;
            min_d2[p] = fminf(min_d2[p], ex * ex + ey * ey);

            // centerline argmin (first-index tie-break, matches jnp.argmin)
            float dxa = px[p] - cp.x, dya = py[p] - cp.y;
            float d2a = dxa * dxa + dya * dya;
            float dxb = px[p] - cp.z, dyb = py[p] - cp.w;
            float d2b = dxb * dxb + dyb * dyb;
            float dmin = d2a; int imin = ia;
            if (d2b < d2a) { dmin = d2b; imin = ia + 1; }  // lower idx on tie
            // within a lane, indices increase with i: strict < keeps first
            if (dmin < best_d2[p] ||
                (dmin == best_d2[p] && imin < best_i[p])) {
                best_d2[p] = dmin; best_i[p] = imin;
            }
        }
    }

    // argmin butterfly across 64 lanes (tie -> lower index)
    #pragma unroll
    for (int off = 1; off <= 32; off <<= 1) {
        #pragma unroll
        for (int p = 0; p < PPW; ++p) {
            float od2 = __shfl_xor(best_d2[p], off);
            int   oi  = __shfl_xor(best_i[p], off);
            if (od2 < best_d2[p] || (od2 == best_d2[p] && oi < best_i[p])) {
                best_d2[p] = od2; best_i[p] = oi;
            }
        }
    }

    // closest centerline point per point (lane-uniform broadcast loads)
    const float2* __restrict__ cl2 = (const float2*)cl4;
    float dax[PPW], day[PPW];
    #pragma unroll
    for (int p = 0; p < PPW; ++p) {
        float2 cc = cl2[best_i[p]];
        dax[p] = cc.x - px[p]; day[p] = cc.y - py[p];   // da = a2 - a1
    }

    // ---- Segment intersection (point -> closest centerline pt) ----
    int hit[PPW] = {0, 0, 0, 0};
    #pragma unroll 2
    for (int i = 0; i < NSEG_PAD / 64; ++i) {
        const int s = lane + (i << 6);
        const int n = s & (cN - 1);
        const int s1 = s + ((n < cN - 1) ? 1 : 0);
        const float2 a  = rb2[s];
        const float2 nx = rb2[s1];
        const float dbx = nx.x - a.x, dby = nx.y - a.y;  // db
        const int valid = (n < cN - 1) ? 1 : 0;

        #pragma unroll
        for (int p = 0; p < PPW; ++p) {
            float dpx = px[p] - a.x, dpy = py[p] - a.y;  // dp = a1 - b1
            float dadb = dax[p] * dby - day[p] * dbx;    // cross(da, db)
            float inv = __builtin_amdgcn_rcpf(dadb + F_EPS);
            float tt = (dax[p] * dpy - day[p] * dpx) * inv;
            float uu = (dbx * dpy - dby * dpx) * inv;
            bool inb = (tt >= 0.0f) & (tt <= 1.0f) & (uu >= 0.0f) & (uu <= 1.0f);
            hit[p] |= valid & (int)inb;
        }
    }

    // ---- reduce min_d2 / hit across 64 lanes ----
    #pragma unroll
    for (int off = 1; off <= 32; off <<= 1) {
        #pragma unroll
        for (int p = 0; p < PPW; ++p) {
            min_d2[p] = fminf(min_d2[p], __shfl_xor(min_d2[p], off));
            hit[p]   |= __shfl_xor(hit[p], off);
        }
    }

    // ---- final loss for this wave's 4 points, one atomic per wave ----
    float total = 0.0f;
    #pragma unroll
    for (int p = 0; p < PPW; ++p) {
        float md = sqrtf(min_d2[p]);
        float sd = hit[p] ? md : -md;               // inside -> negative
        total += fmaxf(sd + F_THRESHOLD, 0.0f);
    }
    if (lane == 0)
        atomicAdd(&out[bc], total);
}

extern "C" void kernel_launch(void* const* d_in, const int* in_sizes, int n_in,
                              void* d_out, int out_size, void* d_ws, size_t ws_size,
                              hipStream_t stream) {
    const float* points      = (const float*)d_in[0];
    const float* boundary    = (const float*)d_in[1];
    const float* centerlines = (const float*)d_in[2];
    float* out = (float*)d_out;
    hipMemsetAsync(out, 0, (size_t)out_size * sizeof(float), stream);
    offroad_kernel<<<cB * cC * G, 256, 0, stream>>>(points, boundary, centerlines, out);
}